// Round 9
// baseline (208.063 us; speedup 1.0000x reference)
//
#include <hip/hip_runtime.h>
#include <math.h>

#define NB 2
#define NL 2048
#define ND 1024
#define NH 16
#define NDH 64
#define NBL 4096   // NB*NL

typedef __attribute__((ext_vector_type(4)))  float f32x4;
typedef __attribute__((ext_vector_type(16))) float f32x16;
typedef __attribute__((ext_vector_type(8)))  short s16x8;
typedef __attribute__((ext_vector_type(4)))  short s16x4;

#define LOG2E 1.44269504088896f

__device__ __forceinline__ float fexp2(float x){
#if __has_builtin(__builtin_amdgcn_exp2f)
  return __builtin_amdgcn_exp2f(x);   // v_exp_f32: computes 2^x
#else
  return exp2f(x);
#endif
}

__device__ __forceinline__ unsigned short f2bf(float f){
  unsigned int u = __float_as_uint(f);
  u += 0x7FFF + ((u >> 16) & 1);   // round-to-nearest-even
  return (unsigned short)(u >> 16);
}

// pack two fp32 -> one dword of 2 bf16 (round-half-up: +0x8000)
__device__ __forceinline__ unsigned int pk2bf(float lo, float hi){
  return __builtin_amdgcn_perm(__float_as_uint(hi) + 0x8000u,
                               __float_as_uint(lo) + 0x8000u, 0x07060302u);
}

// ---- fused fp32->bf16 conversion (x + 4 weights) + rope tables, one launch ----
__global__ void cvt_all(const float* __restrict__ x,
                        const float* __restrict__ wq, const float* __restrict__ wk,
                        const float* __restrict__ wv, const float* __restrict__ wo,
                        unsigned short* __restrict__ xb,
                        unsigned short* __restrict__ wqb, unsigned short* __restrict__ wkb,
                        unsigned short* __restrict__ wvb, unsigned short* __restrict__ wob,
                        float2* __restrict__ qtab, float2* __restrict__ ktab){
  int i = blockIdx.x * blockDim.x + threadIdx.x;
  if (i < (1<<21)){                       // float4 conversion units
    const float* s; unsigned short* d; int off;
    if (i < (1<<20)) { s = x; d = xb; off = i; }
    else {
      int j = i - (1<<20); int w = j >> 18; off = j & ((1<<18)-1);
      s = (w==0)?wq:(w==1)?wk:(w==2)?wv:wo;
      d = (w==0)?wqb:(w==1)?wkb:(w==2)?wvb:wob;
    }
    float4 f = reinterpret_cast<const float4*>(s)[off];
    ushort4 r; r.x=f2bf(f.x); r.y=f2bf(f.y); r.z=f2bf(f.z); r.w=f2bf(f.w);
    reinterpret_cast<ushort4*>(d)[off] = r;
  } else {                                // xPos tables: 65536 entries
    int t = i - (1<<21);
    int l = t >> 5, k = t & 31;
    float half = 2.0f * (float)k;
    float inv_freq = 1.0f / powf(10000.0f, half / 64.0f);
    float fr = (float)l * inv_freq;
    float sv = (half + 0.4f * 64.0f) / (1.4f * 64.0f);
    float pw = ((float)l - 1024.0f) / 512.0f;
    float sc = powf(sv, pw);
    float cs = cosf(fr), sn = sinf(fr);
    qtab[t] = make_float2(cs * sc, sn * sc);
    ktab[t] = make_float2(cs / sc, sn / sc);
  }
}

// ---- fused QKV projection v2: 128x64 tiles (1536 blocks = 6/CU), LDS-bounce epilogue.
//      grid z = 0 (q: rope*scale*log2e/32), 1 (k: rope/scale), 2 (v -> transposed) ----
__global__ __launch_bounds__(256, 4) void gemm_qkv(
    const unsigned short* __restrict__ A,
    const unsigned short* __restrict__ Wq, const float* __restrict__ bq,
    const unsigned short* __restrict__ Wk, const float* __restrict__ bk,
    const unsigned short* __restrict__ Wv, const float* __restrict__ bv,
    unsigned short* __restrict__ qb, unsigned short* __restrict__ kb,
    unsigned short* __restrict__ vtb,
    const float2* __restrict__ qtab, const float2* __restrict__ ktab)
{
  // union: main loop As[128][32] @0 (4096 sh) + Bs[64][32] @4096 (2048 sh);
  //        epilogue T[128][72] overlays @0 (9216 sh = 18 KB)
  __shared__ unsigned short smem[9216];

  const int mode = blockIdx.z;
  const unsigned short* W = (mode==0) ? Wq : (mode==1) ? Wk : Wv;
  const float* bias       = (mode==0) ? bq : (mode==1) ? bk : bv;

  const int tid  = threadIdx.x;
  const int wave = tid >> 6, lane = tid & 63;
  const int m16  = lane & 15, quad = lane >> 4;
  const int mrow = (wave & 1) * 64, ncol = (wave >> 1) * 32;
  const int rA   = lane >> 2, cA = (lane & 3) * 8;
  const int row0 = blockIdx.x * 128, col0 = blockIdx.y * 64;

  f32x4 acc[4][2] = {};

  for (int k0 = 0; k0 < ND; k0 += 32){
    __syncthreads();
#pragma unroll
    for (int i3 = 0; i3 < 3; i3++){
      const int c = wave * 3 + i3;                 // 12 chunks: 8 A + 4 B
      const unsigned short* g; unsigned short* l;
      if (c < 8){ g = A + (size_t)(row0 + c*16 + rA) * ND + k0 + cA;      l = &smem[c*512]; }
      else      { g = W + (size_t)(col0 + (c-8)*16 + rA) * ND + k0 + cA;  l = &smem[4096 + (c-8)*512]; }
      __builtin_amdgcn_global_load_lds((const __attribute__((address_space(1))) void*)g,
                                       (__attribute__((address_space(3))) void*)l, 16, 0, 0);
    }
    __syncthreads();
    s16x8 af[4], bf[2];
#pragma unroll
    for (int mt = 0; mt < 4; mt++)
      af[mt] = *reinterpret_cast<const s16x8*>(&smem[(mrow + mt*16 + m16)*32 + quad*8]);
#pragma unroll
    for (int nt = 0; nt < 2; nt++)
      bf[nt] = *reinterpret_cast<const s16x8*>(&smem[4096 + (ncol + nt*16 + m16)*32 + quad*8]);
#pragma unroll
    for (int mt = 0; mt < 4; mt++)
#pragma unroll
      for (int nt = 0; nt < 2; nt++)
        acc[mt][nt] = __builtin_amdgcn_mfma_f32_16x16x32_bf16(af[mt], bf[nt], acc[mt][nt], 0, 0, 0);
  }
  __syncthreads();   // As/Bs reads done -> safe to overlay T

  const int b  = row0 >> 11, l0 = row0 & (NL - 1);
  const int h  = col0 >> 6;
  const int bh = b * NH + h;

  // epilogue stage 1: all modes write bf16 into T[l][dh] (stride 72)
  if (mode == 2){
#pragma unroll
    for (int mt = 0; mt < 4; mt++)
#pragma unroll
      for (int nt = 0; nt < 2; nt++)
#pragma unroll
        for (int r = 0; r < 4; r++){
          int lrow = mrow + mt*16 + quad*4 + r;
          int dhl  = ncol + nt*16 + m16;
          smem[lrow*72 + dhl] = f2bf(acc[mt][nt][r] + bias[col0 + dhl]);
        }
  } else {
    const float qscale = (mode == 0) ? (0.03125f * LOG2E) : 1.0f;
    const float2* tab  = (mode == 0) ? qtab : ktab;
#pragma unroll
    for (int mt = 0; mt < 4; mt++)
#pragma unroll
      for (int nt = 0; nt < 2; nt++)
#pragma unroll
        for (int r = 0; r < 4; r++){
          int lrow = mrow + mt*16 + quad*4 + r;
          int dhl  = ncol + nt*16 + m16;
          float v  = acc[mt][nt][r] + bias[col0 + dhl];
          float pv = __shfl_xor(v, 1);              // rotation partner (adjacent dh)
          float2 t = tab[(l0 + lrow)*32 + (dhl >> 1)];
          float rh = (dhl & 1) ? pv : -pv;
          smem[lrow*72 + dhl] = f2bf((v * t.x + rh * t.y) * qscale);
        }
  }
  __syncthreads();

  // epilogue stage 2: vectorized copy-out
  if (mode == 2){
    // transposed: vtb[bh][dh][l]
#pragma unroll
    for (int j4 = 0; j4 < 4; j4++){
      int c = tid * 4 + j4;                 // 1024 uint4 chunks (64 dh x 16)
      int d = c >> 4, seg = (c & 15) * 8;
      unsigned short tmp[8];
#pragma unroll
      for (int jj = 0; jj < 8; jj++) tmp[jj] = smem[(seg + jj)*72 + d];
      *reinterpret_cast<uint4*>(vtb + (size_t)(bh * NDH + d) * NL + l0 + seg) =
          *reinterpret_cast<uint4*>(tmp);
    }
  } else {
    // row-major: dst[bh][l][dh], fully coalesced
    unsigned short* dst = ((mode == 0) ? qb : kb) + ((size_t)bh * NL + l0) * NDH;
#pragma unroll
    for (int j = 0; j < 4; j++){
      int idx = j*256 + tid;                // 1024 uint4 chunks (128 l x 8)
      int row = idx >> 3, cg = (idx & 7) * 8;
      *reinterpret_cast<uint4*>(dst + row*NDH + cg) =
          *reinterpret_cast<const uint4*>(&smem[row*72 + cg]);
    }
  }
}

// ---- out projection: 128x64 tile, fp32 output ----
__global__ __launch_bounds__(256) void gemm_o(
    const unsigned short* __restrict__ A, const unsigned short* __restrict__ W,
    const float* __restrict__ bias, float* __restrict__ out)
{
  __shared__ unsigned short As[128][32];
  __shared__ unsigned short Bs[64][32];
  const int tid  = threadIdx.x;
  const int wave = tid >> 6, lane = tid & 63;
  const int m16  = lane & 15, quad = lane >> 4;
  const int mrow = (wave & 1) * 64, ncol = (wave >> 1) * 32;
  const int rA   = lane >> 2, cA = (lane & 3) * 8;
  const int row0 = blockIdx.x * 128, col0 = blockIdx.y * 64;

  f32x4 acc[4][2] = {};

  for (int k0 = 0; k0 < ND; k0 += 32){
    __syncthreads();
#pragma unroll
    for (int i3 = 0; i3 < 3; i3++){
      const int c = wave * 3 + i3;
      const unsigned short* g; unsigned short* l;
      if (c < 8){ g = A + (size_t)(row0 + c*16 + rA) * ND + k0 + cA;      l = &As[c*16][0]; }
      else      { g = W + (size_t)(col0 + (c-8)*16 + rA) * ND + k0 + cA;  l = &Bs[(c-8)*16][0]; }
      __builtin_amdgcn_global_load_lds((const __attribute__((address_space(1))) void*)g,
                                       (__attribute__((address_space(3))) void*)l, 16, 0, 0);
    }
    __syncthreads();
    s16x8 af[4], bf[2];
#pragma unroll
    for (int mt = 0; mt < 4; mt++) af[mt] = *reinterpret_cast<const s16x8*>(&As[mrow + mt*16 + m16][quad*8]);
#pragma unroll
    for (int nt = 0; nt < 2; nt++) bf[nt] = *reinterpret_cast<const s16x8*>(&Bs[ncol + nt*16 + m16][quad*8]);
#pragma unroll
    for (int mt = 0; mt < 4; mt++)
#pragma unroll
      for (int nt = 0; nt < 2; nt++)
        acc[mt][nt] = __builtin_amdgcn_mfma_f32_16x16x32_bf16(af[mt], bf[nt], acc[mt][nt], 0, 0, 0);
  }

#pragma unroll
  for (int mt = 0; mt < 4; mt++)
#pragma unroll
    for (int nt = 0; nt < 2; nt++)
#pragma unroll
      for (int r = 0; r < 4; r++){
        int grow = row0 + mrow + mt*16 + quad*4 + r;
        int gcol = col0 + ncol + nt*16 + m16;
        out[(size_t)grow * ND + gcol] = acc[mt][nt][r] + bias[gcol];
      }
}

// ---- flash attention v6: split-K (z=2 halves of the key range), 256 q/block,
//      64 q/wave, double-buffered K/V LDS, register-fed PV.
//      Linear-combinable partials: no-max softmax => O = sum_z O_z, l = sum_z l_z ----
__global__ __launch_bounds__(256, 2) void attn_kernel(
    const unsigned short* __restrict__ qb,
    const unsigned short* __restrict__ kb,
    const unsigned short* __restrict__ vtb,   // [bh][dh][l]
    unsigned short* __restrict__ opart,       // [2][b][l][h*64+dh] bf16, unnormalized
    float* __restrict__ lsum)                 // [2][bh][q] fp32
{
  __shared__ unsigned short smem[256 * 72];
  const int tid  = threadIdx.x;
  const int wave = tid >> 6, lane = tid & 63;
  const int l31  = lane & 31, g = lane >> 5;
  const int bh   = blockIdx.y;
  const int z    = blockIdx.z;
  const int q0   = blockIdx.x * 256;
  const int kbase = z * (NL / 2);
  const unsigned short* Q  = qb  + (size_t)bh * NL * NDH;
  const unsigned short* K  = kb  + (size_t)bh * NL * NDH;
  const unsigned short* Vt = vtb + (size_t)bh * NDH * NL;

  s16x8 qf[2][4];
#pragma unroll
  for (int q2 = 0; q2 < 2; q2++)
#pragma unroll
    for (int s = 0; s < 4; s++)
      qf[q2][s] = *reinterpret_cast<const s16x8*>(
          Q + (size_t)(q0 + wave*64 + q2*32 + l31) * NDH + s*16 + g*8);

  const int r0 = tid >> 3, c0 = tid & 7;
  const int r1 = r0 + 32;
  const int so0 = r0*64 + ((c0 ^ (r0 & 7)) * 8);
  const int so1 = r1*64 + ((c0 ^ (r1 & 7)) * 8);

  uint4 kreg0 = *reinterpret_cast<const uint4*>(K  + (size_t)(kbase + r0) * NDH + c0*8);
  uint4 kreg1 = *reinterpret_cast<const uint4*>(K  + (size_t)(kbase + r1) * NDH + c0*8);
  uint4 vreg0 = *reinterpret_cast<const uint4*>(Vt + (size_t)r0 * NL + kbase + c0*8);
  uint4 vreg1 = *reinterpret_cast<const uint4*>(Vt + (size_t)r1 * NL + kbase + c0*8);
  *reinterpret_cast<uint4*>(&smem[so0])         = kreg0;
  *reinterpret_cast<uint4*>(&smem[so1])         = kreg1;
  *reinterpret_cast<uint4*>(&smem[8192 + so0])  = vreg0;
  *reinterpret_cast<uint4*>(&smem[8192 + so1])  = vreg1;
  kreg0 = *reinterpret_cast<const uint4*>(K  + (size_t)(kbase + 64 + r0) * NDH + c0*8);
  kreg1 = *reinterpret_cast<const uint4*>(K  + (size_t)(kbase + 64 + r1) * NDH + c0*8);
  vreg0 = *reinterpret_cast<const uint4*>(Vt + (size_t)r0 * NL + kbase + 64 + c0*8);
  vreg1 = *reinterpret_cast<const uint4*>(Vt + (size_t)r1 * NL + kbase + 64 + c0*8);
  __syncthreads();

  float ls[2] = {0.f, 0.f};
  f32x16 ot[2][2] = {};
  const int key7 = l31 & 7;

  for (int kt = 0; kt < 16; kt++){
    const int cur = (kt & 1) * 4096;
    const int nxt = 4096 - cur;
    if (kt < 15){
      *reinterpret_cast<uint4*>(&smem[nxt + so0])        = kreg0;
      *reinterpret_cast<uint4*>(&smem[nxt + so1])        = kreg1;
      *reinterpret_cast<uint4*>(&smem[8192 + nxt + so0]) = vreg0;
      *reinterpret_cast<uint4*>(&smem[8192 + nxt + so1]) = vreg1;
    }
    if (kt < 14){
      const int k0n = kbase + (kt + 2) * 64;
      kreg0 = *reinterpret_cast<const uint4*>(K  + (size_t)(k0n + r0) * NDH + c0*8);
      kreg1 = *reinterpret_cast<const uint4*>(K  + (size_t)(k0n + r1) * NDH + c0*8);
      vreg0 = *reinterpret_cast<const uint4*>(Vt + (size_t)r0 * NL + k0n + c0*8);
      vreg1 = *reinterpret_cast<const uint4*>(Vt + (size_t)r1 * NL + k0n + c0*8);
    }

    const unsigned short* Kb = &smem[cur];
    const unsigned short* Vb = &smem[8192 + cur];

    uint2 pmat[2][8];
#pragma unroll
    for (int t = 0; t < 2; t++){
      f32x16 st0 = {}, st1 = {};
#pragma unroll
      for (int s = 0; s < 4; s++){
        const int cg = (2*s + g) ^ key7;
        s16x8 kf = *reinterpret_cast<const s16x8*>(&Kb[(t*32 + l31)*64 + cg*8]);
        st0 = __builtin_amdgcn_mfma_f32_32x32x16_bf16(kf, qf[0][s], st0, 0, 0, 0);
        st1 = __builtin_amdgcn_mfma_f32_32x32x16_bf16(kf, qf[1][s], st1, 0, 0, 0);
      }
#pragma unroll
      for (int j = 0; j < 4; j++){
        float a0 = fexp2(st0[4*j]), a1 = fexp2(st0[4*j+1]);
        float a2 = fexp2(st0[4*j+2]), a3 = fexp2(st0[4*j+3]);
        ls[0] += (a0 + a1) + (a2 + a3);
        pmat[0][t*4+j].x = pk2bf(a0, a1);
        pmat[0][t*4+j].y = pk2bf(a2, a3);
        float b0 = fexp2(st1[4*j]), b1 = fexp2(st1[4*j+1]);
        float b2 = fexp2(st1[4*j+2]), b3 = fexp2(st1[4*j+3]);
        ls[1] += (b0 + b1) + (b2 + b3);
        pmat[1][t*4+j].x = pk2bf(b0, b1);
        pmat[1][t*4+j].y = pk2bf(b2, b3);
      }
    }

#pragma unroll
    for (int mt = 0; mt < 2; mt++){
      const int dh = mt*32 + l31;
#pragma unroll
      for (int s = 0; s < 8; s++){
        const int cg = s ^ (dh & 7);
        s16x4 vf = *reinterpret_cast<const s16x4*>(&Vb[dh*64 + cg*8 + g*4]);
        ot[mt][0] = __builtin_amdgcn_mfma_f32_32x32x8bf16_1k(
            vf, *reinterpret_cast<s16x4*>(&pmat[0][s]), ot[mt][0], 0, 0, 0);
        ot[mt][1] = __builtin_amdgcn_mfma_f32_32x32x8bf16_1k(
            vf, *reinterpret_cast<s16x4*>(&pmat[1][s]), ot[mt][1], 0, 0, 0);
      }
    }
    __syncthreads();
  }

#pragma unroll
  for (int q2 = 0; q2 < 2; q2++){
    float t = ls[q2] + __shfl_xor(ls[q2], 32);
    if (g == 0)
      lsum[((size_t)z * NB * NH + bh) * NL + q0 + wave*64 + q2*32 + l31] = t;
  }

#pragma unroll
  for (int mt = 0; mt < 2; mt++)
#pragma unroll
    for (int q2 = 0; q2 < 2; q2++)
#pragma unroll
      for (int s = 0; s < 4; s++){
        uint2 pk;
        pk.x = pk2bf(ot[mt][q2][4*s], ot[mt][q2][4*s + 1]);
        pk.y = pk2bf(ot[mt][q2][4*s + 2], ot[mt][q2][4*s + 3]);
        *reinterpret_cast<uint2*>(&smem[(wave*64 + q2*32 + l31)*72 + mt*32 + s*8 + g*4]) = pk;
      }
  __syncthreads();

  const int bb = bh >> 4, h = bh & 15;
  unsigned short* od = opart + (size_t)z * NBL * ND;
#pragma unroll
  for (int j = 0; j < 8; j++){
    int idx = j*256 + tid;
    int row = idx >> 3, cg2 = (idx & 7) * 8;
    *reinterpret_cast<uint4*>(od + ((size_t)(bb*NL + q0 + row)) * ND + h*NDH + cg2) =
        *reinterpret_cast<const uint4*>(&smem[row*72 + cg2]);
  }
}

// ---- combine: out = (O0 + O1) / (l0 + l1), written in-place over opart[0] ----
__device__ __forceinline__ unsigned int comb2(unsigned int a, unsigned int b, float inv){
  float alo = __uint_as_float(a << 16), ahi = __uint_as_float(a & 0xFFFF0000u);
  float blo = __uint_as_float(b << 16), bhi = __uint_as_float(b & 0xFFFF0000u);
  return pk2bf((alo + blo) * inv, (ahi + bhi) * inv);
}

__global__ __launch_bounds__(256) void attn_combine(
    unsigned short* __restrict__ opart, const float* __restrict__ lsum)
{
  int idx = blockIdx.x * 256 + threadIdx.x;
  int row = idx >> 7;
  int col8 = idx & 127;
  int h = col8 >> 3;
  int b = row >> 11, l = row & (NL - 1);
  int bh = b * NH + h;
  float l0 = lsum[(size_t)bh * NL + l];
  float l1 = lsum[(size_t)(NB*NH + bh) * NL + l];
  float inv = 1.0f / (l0 + l1);
  uint4 u0 = reinterpret_cast<const uint4*>(opart)[idx];
  uint4 u1 = reinterpret_cast<const uint4*>(opart + (size_t)NBL * ND)[idx];
  uint4 o;
  o.x = comb2(u0.x, u1.x, inv);
  o.y = comb2(u0.y, u1.y, inv);
  o.z = comb2(u0.z, u1.z, inv);
  o.w = comb2(u0.w, u1.w, inv);
  reinterpret_cast<uint4*>(opart)[idx] = o;
}

extern "C" void kernel_launch(void* const* d_in, const int* in_sizes, int n_in,
                              void* d_out, int out_size, void* d_ws, size_t ws_size,
                              hipStream_t stream)
{
  (void)in_sizes; (void)n_in; (void)out_size; (void)ws_size;
  const float* x  = (const float*)d_in[0];
  const float* Wq = (const float*)d_in[1];
  const float* bq = (const float*)d_in[2];
  const float* Wk = (const float*)d_in[3];
  const float* bk = (const float*)d_in[4];
  const float* Wv = (const float*)d_in[5];
  const float* bv = (const float*)d_in[6];
  const float* Wo = (const float*)d_in[7];
  const float* bo = (const float*)d_in[8];
  float* out = (float*)d_out;

  char* p = (char*)d_ws;
  unsigned short* xb    = (unsigned short*)p; p += (size_t)NBL*ND*2;
  unsigned short* wqb   = (unsigned short*)p; p += (size_t)ND*ND*2;
  unsigned short* wkb   = (unsigned short*)p; p += (size_t)ND*ND*2;
  unsigned short* wvb   = (unsigned short*)p; p += (size_t)ND*ND*2;
  unsigned short* wob   = (unsigned short*)p; p += (size_t)ND*ND*2;
  unsigned short* qbuf  = (unsigned short*)p; p += (size_t)NBL*ND*2;
  unsigned short* kbuf  = (unsigned short*)p; p += (size_t)NBL*ND*2;
  unsigned short* vtb   = (unsigned short*)p; p += (size_t)NBL*ND*2;
  unsigned short* opart = (unsigned short*)p; p += (size_t)2*NBL*ND*2;
  float* lsum = (float*)p; p += (size_t)2*NB*NH*NL*4;
  float2* qtab = (float2*)p; p += (size_t)NL*32*8;
  float2* ktab = (float2*)p; p += (size_t)NL*32*8;

  // 2M cvt units + 64K rope units = 8448 blocks
  hipLaunchKernelGGL(cvt_all, dim3(8448), dim3(256), 0, stream,
                     x, Wq, Wk, Wv, Wo, xb, wqb, wkb, wvb, wob, qtab, ktab);

  // NOTE the reference's swap: k uses (Wv,bv), v uses (Wk,bk)
  hipLaunchKernelGGL(gemm_qkv, dim3(NBL/128, ND/64, 3), dim3(256), 0, stream,
                     xb, wqb, bq, wvb, bv, wkb, bk, qbuf, kbuf, vtb, qtab, ktab);

  hipLaunchKernelGGL(attn_kernel, dim3(NL/256, NB*NH, 2), dim3(256), 0, stream,
                     qbuf, kbuf, vtb, opart, lsum);
  hipLaunchKernelGGL(attn_combine, dim3(NBL*ND/8/256), dim3(256), 0, stream, opart, lsum);

  hipLaunchKernelGGL(gemm_o, dim3(NBL/128, ND/64), dim3(256), 0, stream, opart, wob, bo, out);
}